// Round 1
// baseline (564.751 us; speedup 1.0000x reference)
//
#include <hip/hip_runtime.h>

#define NN    8192
#define NG    64
#define NPG   128
#define KNN   100
#define FIN   6
#define WID   128
#define D2    768
#define NEG   0.01f
#define INV101 (1.0f/101.0f)
#define BNEPS 1e-5f
#define BIG   1e30f

__device__ __forceinline__ float leaky(float v) { return v > 0.f ? v : NEG * v; }

// ---------------- K1: kNN (rank-select) + normalized adjacency A = (I+M)/101 ----------------
// grid 256 (4 blocks/graph, 32 rows each), block 256
__global__ __launch_bounds__(256) void k_knn(const float* __restrict__ x, float* __restrict__ A)
{
    int g  = blockIdx.x >> 2;
    int i0 = (blockIdx.x & 3) * 32;
    __shared__ float xg[NPG * FIN];
    __shared__ float sq[NPG];
    __shared__ float D[32][NPG];
    const float* xp = x + g * NPG * FIN;
    for (int t = threadIdx.x; t < NPG * FIN; t += 256) xg[t] = xp[t];
    __syncthreads();
    if (threadIdx.x < NPG) {
        float s = 0.f;
        #pragma unroll
        for (int c = 0; c < FIN; ++c) { float v = xg[threadIdx.x * FIN + c]; s = fmaf(v, v, s); }
        sq[threadIdx.x] = s;
    }
    __syncthreads();
    for (int e = threadIdx.x; e < 32 * NPG; e += 256) {
        int il = e >> 7, j = e & 127;
        int i = i0 + il;
        float d;
        if (j == i) d = BIG;
        else {
            float dot = 0.f;
            #pragma unroll
            for (int c = 0; c < FIN; ++c) dot = fmaf(xg[i * FIN + c], xg[j * FIN + c], dot);
            d = sq[i] + sq[j] - 2.f * dot;
        }
        D[il][j] = d;
    }
    __syncthreads();
    float* Ag = A + (size_t)g * NPG * NPG;
    for (int e = threadIdx.x; e < 32 * NPG; e += 256) {
        int il = e >> 7, j = e & 127;
        int i = i0 + il;
        float aval;
        if (i == j) aval = INV101;
        else {
            float dj = D[il][j];
            int cnt = 0;
            #pragma unroll 4
            for (int k = 0; k < NPG; ++k) {
                float dk = D[il][k];
                cnt += (dk < dj || (dk == dj && k < j)) ? 1 : 0;
            }
            aval = (cnt < KNN) ? INV101 : 0.f;
        }
        Ag[i * NPG + j] = aval;
    }
}

// ---------------- K2: A <- A @ A  (per graph, in place; reads staged to LDS first) ----------------
// grid 64, block 256; each thread an 8x8 tile
__global__ __launch_bounds__(256) void k_sqA(float* __restrict__ A)
{
    int g = blockIdx.x;
    __shared__ float As[NPG * 129];  // padded: a-reads conflict-free
    __shared__ float Bs[NPG * 132];  // padded: float4-aligned b-reads
    float* Ag = A + (size_t)g * NPG * NPG;
    for (int t = threadIdx.x; t < NPG * NPG; t += 256) {
        int r = t >> 7, c = t & 127;
        float v = Ag[t];
        As[r * 129 + c] = v;
        Bs[r * 132 + c] = v;
    }
    __syncthreads();
    int ty = threadIdx.x >> 4, tx = threadIdx.x & 15;
    int ri = ty * 8, cj = tx * 8;
    float acc[8][8] = {};
    for (int k = 0; k < NPG; ++k) {
        float a[8], bb[8];
        #pragma unroll
        for (int r = 0; r < 8; ++r) a[r] = As[(ri + r) * 129 + k];
        float4 b0 = *(const float4*)&Bs[k * 132 + cj];
        float4 b1 = *(const float4*)&Bs[k * 132 + cj + 4];
        bb[0]=b0.x; bb[1]=b0.y; bb[2]=b0.z; bb[3]=b0.w;
        bb[4]=b1.x; bb[5]=b1.y; bb[6]=b1.z; bb[7]=b1.w;
        #pragma unroll
        for (int r = 0; r < 8; ++r)
            #pragma unroll
            for (int c = 0; c < 8; ++c)
                acc[r][c] = fmaf(a[r], bb[c], acc[r][c]);
    }
    #pragma unroll
    for (int r = 0; r < 8; ++r) {
        float4 v0 = {acc[r][0], acc[r][1], acc[r][2], acc[r][3]};
        float4 v1 = {acc[r][4], acc[r][5], acc[r][6], acc[r][7]};
        *(float4*)&Ag[(ri + r) * NPG + cj]     = v0;
        *(float4*)&Ag[(ri + r) * NPG + cj + 4] = v1;
    }
}

// ---------------- K3: conv1 = leaky(A2 @ x @ W1 + b1), + pool into Z[:,0:256] ----------------
__global__ __launch_bounds__(256) void k_conv1(const float* __restrict__ x, const float* __restrict__ A2,
                                               const float* __restrict__ W1, const float* __restrict__ b1,
                                               float* __restrict__ H, float* __restrict__ Z)
{
    int g = blockIdx.x;
    __shared__ float xg[NPG * FIN];
    __shared__ float p2[NPG * FIN];
    __shared__ float hs[NPG * 132];
    const float* xp = x + g * NPG * FIN;
    for (int t = threadIdx.x; t < NPG * FIN; t += 256) xg[t] = xp[t];
    __syncthreads();
    const float* A2g = A2 + (size_t)g * NPG * NPG;
    for (int e = threadIdx.x; e < NPG * FIN; e += 256) {
        int i = e / FIN, d = e - i * FIN;
        float s = 0.f;
        for (int k = 0; k < NPG; ++k) s = fmaf(A2g[i * NPG + k], xg[k * FIN + d], s);
        p2[e] = s;
    }
    __syncthreads();
    for (int e = threadIdx.x; e < NPG * WID; e += 256) {
        int i = e >> 7, o = e & 127;
        float s = b1[o];
        #pragma unroll
        for (int d = 0; d < FIN; ++d) s = fmaf(p2[i * FIN + d], W1[d * WID + o], s);
        s = leaky(s);
        H[(size_t)(g * NPG + i) * WID + o] = s;
        hs[i * 132 + o] = s;
    }
    __syncthreads();
    if (threadIdx.x < WID) {
        int o = threadIdx.x;
        float sm = 0.f, mx = -BIG;
        for (int i = 0; i < NPG; ++i) { float v = hs[i * 132 + o]; sm += v; mx = fmaxf(mx, v); }
        Z[g * D2 + o]       = sm * (1.f / NPG);
        Z[g * D2 + WID + o] = mx;
    }
}

// ---------------- K4/K5: conv f = leaky(A2 @ h @ W + b), + pool; H update in place ----------------
__global__ __launch_bounds__(256) void k_conv(const float* __restrict__ A2, const float* __restrict__ Hin,
                                              const float* __restrict__ W, const float* __restrict__ bias,
                                              float* __restrict__ Hout, float* __restrict__ Z,
                                              int zoff, int writeH)
{
    int g = blockIdx.x;
    __shared__ float Ps[NPG * 129];  // holds A2, then P = A2 @ h
    __shared__ float hs[NPG * 132];  // holds h, then h' (for pooling)
    const float* A2g = A2 + (size_t)g * NPG * NPG;
    const float* hg  = Hin + (size_t)g * NPG * WID;
    for (int t = threadIdx.x; t < NPG * NPG; t += 256) {
        int r = t >> 7, c = t & 127;
        Ps[r * 129 + c] = A2g[t];
        hs[r * 132 + c] = hg[t];
    }
    __syncthreads();
    int ty = threadIdx.x >> 4, tx = threadIdx.x & 15;
    int ri = ty * 8, cj = tx * 8;
    {   // P = A2 @ h
        float acc[8][8] = {};
        for (int k = 0; k < NPG; ++k) {
            float a[8], bb[8];
            #pragma unroll
            for (int r = 0; r < 8; ++r) a[r] = Ps[(ri + r) * 129 + k];
            float4 b0 = *(const float4*)&hs[k * 132 + cj];
            float4 b1 = *(const float4*)&hs[k * 132 + cj + 4];
            bb[0]=b0.x; bb[1]=b0.y; bb[2]=b0.z; bb[3]=b0.w;
            bb[4]=b1.x; bb[5]=b1.y; bb[6]=b1.z; bb[7]=b1.w;
            #pragma unroll
            for (int r = 0; r < 8; ++r)
                #pragma unroll
                for (int c = 0; c < 8; ++c)
                    acc[r][c] = fmaf(a[r], bb[c], acc[r][c]);
        }
        __syncthreads();
        #pragma unroll
        for (int r = 0; r < 8; ++r)
            #pragma unroll
            for (int c = 0; c < 8; ++c)
                Ps[(ri + r) * 129 + cj + c] = acc[r][c];
        __syncthreads();
    }
    {   // h' = leaky(P @ W + b)
        float acc[8][8] = {};
        for (int d = 0; d < NPG; ++d) {
            float a[8], bb[8];
            #pragma unroll
            for (int r = 0; r < 8; ++r) a[r] = Ps[(ri + r) * 129 + d];
            float4 w0 = *(const float4*)&W[d * WID + cj];
            float4 w1 = *(const float4*)&W[d * WID + cj + 4];
            bb[0]=w0.x; bb[1]=w0.y; bb[2]=w0.z; bb[3]=w0.w;
            bb[4]=w1.x; bb[5]=w1.y; bb[6]=w1.z; bb[7]=w1.w;
            #pragma unroll
            for (int r = 0; r < 8; ++r)
                #pragma unroll
                for (int c = 0; c < 8; ++c)
                    acc[r][c] = fmaf(a[r], bb[c], acc[r][c]);
        }
        #pragma unroll
        for (int r = 0; r < 8; ++r) {
            float4 v0, v1;
            v0.x = leaky(acc[r][0] + bias[cj + 0]);
            v0.y = leaky(acc[r][1] + bias[cj + 1]);
            v0.z = leaky(acc[r][2] + bias[cj + 2]);
            v0.w = leaky(acc[r][3] + bias[cj + 3]);
            v1.x = leaky(acc[r][4] + bias[cj + 4]);
            v1.y = leaky(acc[r][5] + bias[cj + 5]);
            v1.z = leaky(acc[r][6] + bias[cj + 6]);
            v1.w = leaky(acc[r][7] + bias[cj + 7]);
            *(float4*)&hs[(ri + r) * 132 + cj]     = v0;
            *(float4*)&hs[(ri + r) * 132 + cj + 4] = v1;
            if (writeH) {
                *(float4*)&Hout[(size_t)(g * NPG + ri + r) * WID + cj]     = v0;
                *(float4*)&Hout[(size_t)(g * NPG + ri + r) * WID + cj + 4] = v1;
            }
        }
    }
    __syncthreads();
    if (threadIdx.x < WID) {
        int o = threadIdx.x;
        float sm = 0.f, mx = -BIG;
        for (int i = 0; i < NPG; ++i) { float v = hs[i * 132 + o]; sm += v; mx = fmaxf(mx, v); }
        Z[g * D2 + zoff + o]       = sm * (1.f / NPG);
        Z[g * D2 + zoff + WID + o] = mx;
    }
}

// ---------------- K6: BatchNorm (batch stats) + transpose to ZT[768][64] ----------------
__global__ __launch_bounds__(D2) void k_bn(const float* __restrict__ Zp, const float* __restrict__ gam,
                                           const float* __restrict__ bet, float* __restrict__ ZT)
{
    int c = threadIdx.x;
    float s = 0.f, s2 = 0.f;
    for (int r = 0; r < NG; ++r) { float v = Zp[r * D2 + c]; s += v; s2 = fmaf(v, v, s2); }
    float m   = s * (1.f / NG);
    float var = s2 * (1.f / NG) - m * m;
    float sc  = rsqrtf(var + BNEPS) * gam[c];
    float bt  = bet[c];
    for (int r = 0; r < NG; ++r) {
        float v = Zp[r * D2 + c];
        ZT[c * NG + r] = (v - m) * sc + bt;
    }
}

// ---------------- K7: one MLP layer, transposed activations ----------------
// grid 96 (8 cols each), block 256: 4 waves x 2 cols; lanes = rows (coalesced), W via scalar loads
__global__ __launch_bounds__(256) void k_lin(const float* __restrict__ ZTin, const float* __restrict__ W,
                                             const float* __restrict__ bias, float* __restrict__ ZTout)
{
    int c0 = blockIdx.x * 8 + (threadIdx.x >> 6) * 2;
    c0 = __builtin_amdgcn_readfirstlane(c0);
    int r = threadIdx.x & 63;
    float s0 = bias[c0], s1 = bias[c0 + 1];
    #pragma unroll 4
    for (int k = 0; k < D2; ++k) {
        float zv = ZTin[k * NG + r];
        s0 = fmaf(zv, W[k * D2 + c0], s0);
        s1 = fmaf(zv, W[k * D2 + c0 + 1], s1);
    }
    ZTout[c0 * NG + r]       = leaky(s0);
    ZTout[(c0 + 1) * NG + r] = leaky(s1);
}

// ---------------- K8: output head ----------------
__global__ __launch_bounds__(64) void k_out(const float* __restrict__ ZTin, const float* __restrict__ W,
                                            const float* __restrict__ bias, float* __restrict__ out)
{
    int r = threadIdx.x;
    float s = bias[0];
    #pragma unroll 4
    for (int k = 0; k < D2; ++k) s = fmaf(ZTin[k * NG + r], W[k], s);
    out[r] = s;
}

extern "C" void kernel_launch(void* const* d_in, const int* in_sizes, int n_in,
                              void* d_out, int out_size, void* d_ws, size_t ws_size,
                              hipStream_t stream)
{
    (void)in_sizes; (void)n_in; (void)out_size; (void)ws_size;
    const float* x       = (const float*)d_in[0];
    // d_in[1] = batch: structure is fixed (i / 128), unused
    const float* conv1_W = (const float*)d_in[2];
    const float* conv1_b = (const float*)d_in[3];
    const float* convs_W = (const float*)d_in[4];
    const float* convs_b = (const float*)d_in[5];
    const float* bn_g    = (const float*)d_in[6];
    const float* bn_b    = (const float*)d_in[7];
    const float* lin_W   = (const float*)d_in[8];
    const float* lin_b   = (const float*)d_in[9];
    const float* out_W   = (const float*)d_in[10];
    const float* out_b   = (const float*)d_in[11];

    // workspace layout (floats): A/A2 (1M), H (1M), Zp (48K), ZT0, ZT1  ~= 9 MB
    float* A   = (float*)d_ws;
    float* H   = A + (1 << 20);
    float* Zp  = H + (1 << 20);
    float* ZT0 = Zp + NG * D2;
    float* ZT1 = ZT0 + NG * D2;

    k_knn  <<<dim3(256), dim3(256), 0, stream>>>(x, A);
    k_sqA  <<<dim3(NG),  dim3(256), 0, stream>>>(A);                       // A <- A^2 (in place)
    k_conv1<<<dim3(NG),  dim3(256), 0, stream>>>(x, A, conv1_W, conv1_b, H, Zp);
    k_conv <<<dim3(NG),  dim3(256), 0, stream>>>(A, H, convs_W,              convs_b,       H, Zp, 256, 1);
    k_conv <<<dim3(NG),  dim3(256), 0, stream>>>(A, H, convs_W + WID * WID,  convs_b + WID, H, Zp, 512, 0);
    k_bn   <<<dim3(1),   dim3(D2),  0, stream>>>(Zp, bn_g, bn_b, ZT0);

    const float* zin = ZT0; float* zout = ZT1;
    for (int l = 0; l < 5; ++l) {
        k_lin<<<dim3(96), dim3(256), 0, stream>>>(zin, lin_W + (size_t)l * D2 * D2, lin_b + l * D2, zout);
        float* t = zout; zout = (float*)zin; zin = t;
    }
    k_out<<<dim3(1), dim3(64), 0, stream>>>(zin, out_W, out_b, (float*)d_out);
}

// Round 2
// 408.073 us; speedup vs baseline: 1.3839x; 1.3839x over previous
//
#include <hip/hip_runtime.h>

#define NN    8192
#define NG    64
#define NPG   128
#define KNN   100
#define FIN   6
#define WID   128
#define D2    768
#define NEG   0.01f
#define INV101 (1.0f/101.0f)
#define BNEPS 1e-5f
#define BIG   1e30f

__device__ __forceinline__ float leaky(float v) { return v > 0.f ? v : NEG * v; }

// ---------------- K1: kNN (rank-select) + normalized adjacency A = (I+M)/101 ----------------
// grid 512 (8 blocks/graph, 16 rows each), block 256
__global__ __launch_bounds__(256) void k_knn(const float* __restrict__ x, float* __restrict__ A)
{
    int g  = blockIdx.x >> 3;
    int i0 = (blockIdx.x & 7) * 16;
    __shared__ float xg[NPG * FIN];
    __shared__ float sq[NPG];
    __shared__ float D[16][NPG];
    const float* xp = x + g * NPG * FIN;
    for (int t = threadIdx.x; t < NPG * FIN; t += 256) xg[t] = xp[t];
    __syncthreads();
    if (threadIdx.x < NPG) {
        float s = 0.f;
        #pragma unroll
        for (int c = 0; c < FIN; ++c) { float v = xg[threadIdx.x * FIN + c]; s = fmaf(v, v, s); }
        sq[threadIdx.x] = s;
    }
    __syncthreads();
    for (int e = threadIdx.x; e < 16 * NPG; e += 256) {
        int il = e >> 7, j = e & 127;
        int i = i0 + il;
        float d;
        if (j == i) d = BIG;
        else {
            float dot = 0.f;
            #pragma unroll
            for (int c = 0; c < FIN; ++c) dot = fmaf(xg[i * FIN + c], xg[j * FIN + c], dot);
            d = sq[i] + sq[j] - 2.f * dot;
        }
        D[il][j] = d;
    }
    __syncthreads();
    float* Ag = A + (size_t)g * NPG * NPG;
    for (int e = threadIdx.x; e < 16 * NPG; e += 256) {
        int il = e >> 7, j = e & 127;
        int i = i0 + il;
        float aval;
        if (i == j) aval = INV101;
        else {
            float dj = D[il][j];
            int cnt = 0;
            #pragma unroll 8
            for (int k = 0; k < NPG; ++k) {
                float dk = D[il][k];
                cnt += (dk < dj || (dk == dj && k < j)) ? 1 : 0;
            }
            aval = (cnt < KNN) ? INV101 : 0.f;
        }
        Ag[i * NPG + j] = aval;
    }
}

// ---------------- K2: A2 = A @ A  (per graph; 2 blocks/graph, 64 rows each) ----------------
__global__ __launch_bounds__(256) void k_sqA(const float* __restrict__ A, float* __restrict__ A2)
{
    int g = blockIdx.x >> 1;
    int i0 = (blockIdx.x & 1) * 64;
    __shared__ float As[64 * 129];
    __shared__ float Bs[NPG * 132];
    const float* Ag = A + (size_t)g * NPG * NPG;
    for (int t = threadIdx.x; t < NPG * NPG; t += 256) {
        int r = t >> 7, c = t & 127;
        Bs[r * 132 + c] = Ag[t];
    }
    for (int t = threadIdx.x; t < 64 * NPG; t += 256) {
        int r = t >> 7, c = t & 127;
        As[r * 129 + c] = Ag[(i0 + r) * NPG + c];
    }
    __syncthreads();
    int ty = threadIdx.x >> 4, tx = threadIdx.x & 15;
    int lr = ty * 4, cj = tx * 8;
    float acc[4][8] = {};
    for (int k = 0; k < NPG; ++k) {
        float a[4], bb[8];
        #pragma unroll
        for (int r = 0; r < 4; ++r) a[r] = As[(lr + r) * 129 + k];
        float4 b0 = *(const float4*)&Bs[k * 132 + cj];
        float4 b1 = *(const float4*)&Bs[k * 132 + cj + 4];
        bb[0]=b0.x; bb[1]=b0.y; bb[2]=b0.z; bb[3]=b0.w;
        bb[4]=b1.x; bb[5]=b1.y; bb[6]=b1.z; bb[7]=b1.w;
        #pragma unroll
        for (int r = 0; r < 4; ++r)
            #pragma unroll
            for (int c = 0; c < 8; ++c)
                acc[r][c] = fmaf(a[r], bb[c], acc[r][c]);
    }
    float* A2g = A2 + (size_t)g * NPG * NPG;
    #pragma unroll
    for (int r = 0; r < 4; ++r) {
        float4 v0 = {acc[r][0], acc[r][1], acc[r][2], acc[r][3]};
        float4 v1 = {acc[r][4], acc[r][5], acc[r][6], acc[r][7]};
        *(float4*)&A2g[(i0 + lr + r) * NPG + cj]     = v0;
        *(float4*)&A2g[(i0 + lr + r) * NPG + cj + 4] = v1;
    }
}

// ---------------- K3: conv1 = leaky(A2 @ x @ W1 + b1) -> H ----------------
__global__ __launch_bounds__(256) void k_conv1(const float* __restrict__ x, const float* __restrict__ A2,
                                               const float* __restrict__ W1, const float* __restrict__ b1,
                                               float* __restrict__ H)
{
    int g = blockIdx.x;
    __shared__ float xg[NPG * FIN];
    __shared__ float p2[NPG * FIN];
    const float* xp = x + g * NPG * FIN;
    for (int t = threadIdx.x; t < NPG * FIN; t += 256) xg[t] = xp[t];
    __syncthreads();
    const float* A2g = A2 + (size_t)g * NPG * NPG;
    for (int e = threadIdx.x; e < NPG * FIN; e += 256) {
        int i = e / FIN, d = e - i * FIN;
        float s = 0.f;
        for (int k = 0; k < NPG; ++k) s = fmaf(A2g[i * NPG + k], xg[k * FIN + d], s);
        p2[e] = s;
    }
    __syncthreads();
    for (int e = threadIdx.x; e < NPG * WID; e += 256) {
        int i = e >> 7, o = e & 127;
        float s = b1[o];
        #pragma unroll
        for (int d = 0; d < FIN; ++d) s = fmaf(p2[i * FIN + d], W1[d * WID + o], s);
        H[(size_t)(g * NPG + i) * WID + o] = leaky(s);
    }
}

// ---------------- K4/K5: conv = leaky(A2 @ h @ W + b); pools PREVIOUS h at zoff ----------------
// grid 128 (2 blocks/graph, 64 output rows each), block 256
__global__ __launch_bounds__(256) void k_conv(const float* __restrict__ A2, const float* __restrict__ Hin,
                                              const float* __restrict__ W, const float* __restrict__ bias,
                                              float* __restrict__ Hout, float* __restrict__ Zp, int zoff)
{
    int g = blockIdx.x >> 1;
    int i0 = (blockIdx.x & 1) * 64;
    __shared__ float Ps[64 * 129];   // A2 half-rows, then P = A2 @ h
    __shared__ float hs[NPG * 132];  // full input h
    const float* A2g = A2 + (size_t)g * NPG * NPG + (size_t)i0 * NPG;
    const float* hg  = Hin + (size_t)g * NPG * WID;
    for (int t = threadIdx.x; t < NPG * WID; t += 256) {
        int r = t >> 7, c = t & 127;
        hs[r * 132 + c] = hg[t];
    }
    for (int t = threadIdx.x; t < 64 * NPG; t += 256) {
        int r = t >> 7, c = t & 127;
        Ps[r * 129 + c] = A2g[t];
    }
    __syncthreads();
    // fused pool of the INPUT h (previous layer's output); one block per graph does it
    if (i0 == 0 && threadIdx.x < WID) {
        int o = threadIdx.x;
        float sm = 0.f, mx = -BIG;
        for (int i = 0; i < NPG; ++i) { float v = hs[i * 132 + o]; sm += v; mx = fmaxf(mx, v); }
        Zp[g * D2 + zoff + o]       = sm * (1.f / NPG);
        Zp[g * D2 + zoff + WID + o] = mx;
    }
    int ty = threadIdx.x >> 4, tx = threadIdx.x & 15;
    int lr = ty * 4, cj = tx * 8;
    {   // P = A2 @ h  (64x128)
        float acc[4][8] = {};
        for (int k = 0; k < NPG; ++k) {
            float a[4], bb[8];
            #pragma unroll
            for (int r = 0; r < 4; ++r) a[r] = Ps[(lr + r) * 129 + k];
            float4 b0 = *(const float4*)&hs[k * 132 + cj];
            float4 b1 = *(const float4*)&hs[k * 132 + cj + 4];
            bb[0]=b0.x; bb[1]=b0.y; bb[2]=b0.z; bb[3]=b0.w;
            bb[4]=b1.x; bb[5]=b1.y; bb[6]=b1.z; bb[7]=b1.w;
            #pragma unroll
            for (int r = 0; r < 4; ++r)
                #pragma unroll
                for (int c = 0; c < 8; ++c)
                    acc[r][c] = fmaf(a[r], bb[c], acc[r][c]);
        }
        __syncthreads();
        #pragma unroll
        for (int r = 0; r < 4; ++r)
            #pragma unroll
            for (int c = 0; c < 8; ++c)
                Ps[(lr + r) * 129 + cj + c] = acc[r][c];
        __syncthreads();
    }
    {   // h' = leaky(P @ W + b) -> Hout
        float acc[4][8] = {};
        for (int d = 0; d < NPG; ++d) {
            float a[4], bb[8];
            #pragma unroll
            for (int r = 0; r < 4; ++r) a[r] = Ps[(lr + r) * 129 + d];
            float4 w0 = *(const float4*)&W[d * WID + cj];
            float4 w1 = *(const float4*)&W[d * WID + cj + 4];
            bb[0]=w0.x; bb[1]=w0.y; bb[2]=w0.z; bb[3]=w0.w;
            bb[4]=w1.x; bb[5]=w1.y; bb[6]=w1.z; bb[7]=w1.w;
            #pragma unroll
            for (int r = 0; r < 4; ++r)
                #pragma unroll
                for (int c = 0; c < 8; ++c)
                    acc[r][c] = fmaf(a[r], bb[c], acc[r][c]);
        }
        #pragma unroll
        for (int r = 0; r < 4; ++r) {
            float4 v0, v1;
            v0.x = leaky(acc[r][0] + bias[cj + 0]);
            v0.y = leaky(acc[r][1] + bias[cj + 1]);
            v0.z = leaky(acc[r][2] + bias[cj + 2]);
            v0.w = leaky(acc[r][3] + bias[cj + 3]);
            v1.x = leaky(acc[r][4] + bias[cj + 4]);
            v1.y = leaky(acc[r][5] + bias[cj + 5]);
            v1.z = leaky(acc[r][6] + bias[cj + 6]);
            v1.w = leaky(acc[r][7] + bias[cj + 7]);
            *(float4*)&Hout[(size_t)(g * NPG + i0 + lr + r) * WID + cj]     = v0;
            *(float4*)&Hout[(size_t)(g * NPG + i0 + lr + r) * WID + cj + 4] = v1;
        }
    }
}

// ---------------- K6: pool of final h -> Zp[:, zoff..zoff+256) ----------------
__global__ __launch_bounds__(128) void k_pool(const float* __restrict__ H, float* __restrict__ Zp, int zoff)
{
    int g = blockIdx.x, o = threadIdx.x;
    float sm = 0.f, mx = -BIG;
    for (int i = 0; i < NPG; ++i) {
        float v = H[((size_t)g * NPG + i) * WID + o];
        sm += v; mx = fmaxf(mx, v);
    }
    Zp[g * D2 + zoff + o]       = sm * (1.f / NPG);
    Zp[g * D2 + zoff + WID + o] = mx;
}

// ---------------- K7: BatchNorm (batch stats) + transpose to ZT[768][64] ----------------
__global__ __launch_bounds__(D2) void k_bn(const float* __restrict__ Zp, const float* __restrict__ gam,
                                           const float* __restrict__ bet, float* __restrict__ ZT)
{
    int c = threadIdx.x;
    float s = 0.f, s2 = 0.f;
    for (int r = 0; r < NG; ++r) { float v = Zp[r * D2 + c]; s += v; s2 = fmaf(v, v, s2); }
    float m   = s * (1.f / NG);
    float var = s2 * (1.f / NG) - m * m;
    float sc  = rsqrtf(var + BNEPS) * gam[c];
    float bt  = bet[c];
    for (int r = 0; r < NG; ++r) {
        float v = Zp[r * D2 + c];
        ZT[c * NG + r] = (v - m) * sc + bt;
    }
}

// ---------------- K8: one MLP layer ----------------
// grid 96 (8-col slab each), block 256: lane%8 = col (coalesced W row reads), 2 rows/thread
__global__ __launch_bounds__(256) void k_lin(const float* __restrict__ ZTin, const float* __restrict__ W,
                                             const float* __restrict__ bias, float* __restrict__ ZTout)
{
    int c = blockIdx.x * 8 + (threadIdx.x & 7);
    int r = (threadIdx.x >> 3) * 2;
    float s0 = 0.f, s1 = 0.f;
    #pragma unroll 16
    for (int k = 0; k < D2; ++k) {
        float wv = W[k * D2 + c];
        float2 z = *(const float2*)&ZTin[k * NG + r];
        s0 = fmaf(z.x, wv, s0);
        s1 = fmaf(z.y, wv, s1);
    }
    float bv = bias[c];
    ZTout[c * NG + r]     = leaky(s0 + bv);
    ZTout[c * NG + r + 1] = leaky(s1 + bv);
}

// ---------------- K9: output head (split-K across 4 waves) ----------------
__global__ __launch_bounds__(256) void k_out(const float* __restrict__ ZTin, const float* __restrict__ W,
                                             const float* __restrict__ bias, float* __restrict__ out)
{
    __shared__ float red[4][64];
    int r = threadIdx.x & 63, q = threadIdx.x >> 6;
    float s = 0.f;
    #pragma unroll 8
    for (int k = q * 192; k < q * 192 + 192; ++k)
        s = fmaf(ZTin[k * NG + r], W[k], s);
    red[q][r] = s;
    __syncthreads();
    if (threadIdx.x < 64)
        out[r] = red[0][r] + red[1][r] + red[2][r] + red[3][r] + bias[0];
}

extern "C" void kernel_launch(void* const* d_in, const int* in_sizes, int n_in,
                              void* d_out, int out_size, void* d_ws, size_t ws_size,
                              hipStream_t stream)
{
    (void)in_sizes; (void)n_in; (void)out_size; (void)ws_size;
    const float* x       = (const float*)d_in[0];
    // d_in[1] = batch: structure is fixed (i / 128), unused
    const float* conv1_W = (const float*)d_in[2];
    const float* conv1_b = (const float*)d_in[3];
    const float* convs_W = (const float*)d_in[4];
    const float* convs_b = (const float*)d_in[5];
    const float* bn_g    = (const float*)d_in[6];
    const float* bn_b    = (const float*)d_in[7];
    const float* lin_W   = (const float*)d_in[8];
    const float* lin_b   = (const float*)d_in[9];
    const float* out_W   = (const float*)d_in[10];
    const float* out_b   = (const float*)d_in[11];

    // workspace (floats): A_raw (1M, reused as H_b), A2 (1M), H_a (1M), Zp, ZT0, ZT1  ~= 12.8 MB
    float* A_raw = (float*)d_ws;
    float* A2    = A_raw + (1 << 20);
    float* H_a   = A2 + (1 << 20);
    float* H_b   = A_raw;            // A_raw dead after k_sqA
    float* Zp    = H_a + (1 << 20);
    float* ZT0   = Zp + NG * D2;
    float* ZT1   = ZT0 + NG * D2;

    k_knn  <<<dim3(512), dim3(256), 0, stream>>>(x, A_raw);
    k_sqA  <<<dim3(128), dim3(256), 0, stream>>>(A_raw, A2);
    k_conv1<<<dim3(NG),  dim3(256), 0, stream>>>(x, A2, conv1_W, conv1_b, H_a);
    k_conv <<<dim3(128), dim3(256), 0, stream>>>(A2, H_a, convs_W,             convs_b,       H_b, Zp, 0);
    k_conv <<<dim3(128), dim3(256), 0, stream>>>(A2, H_b, convs_W + WID * WID, convs_b + WID, H_a, Zp, 256);
    k_pool <<<dim3(NG),  dim3(128), 0, stream>>>(H_a, Zp, 512);
    k_bn   <<<dim3(1),   dim3(D2),  0, stream>>>(Zp, bn_g, bn_b, ZT0);

    const float* zin = ZT0; float* zout = ZT1;
    for (int l = 0; l < 5; ++l) {
        k_lin<<<dim3(96), dim3(256), 0, stream>>>(zin, lin_W + (size_t)l * D2 * D2, lin_b + l * D2, zout);
        float* t = zout; zout = (float*)zin; zin = t;
    }
    k_out<<<dim3(1), dim3(256), 0, stream>>>(zin, out_W, out_b, (float*)d_out);
}

// Round 3
// 191.283 us; speedup vs baseline: 2.9524x; 2.1334x over previous
//
#include <hip/hip_runtime.h>

#define NN    8192
#define NG    64
#define NPG   128
#define KNN   100
#define FIN   6
#define WID   128
#define D2    768
#define NEG   0.01f
#define INV101 (1.0f/101.0f)
#define BNEPS 1e-5f
#define BIG   1e30f

__device__ __forceinline__ float leaky(float v) { return v > 0.f ? v : NEG * v; }

// ---------------- K1: kNN (rank-select) + normalized adjacency A = (I+M)/101 ----------------
// grid 512 (8 blocks/graph, 16 rows each), block 256
__global__ __launch_bounds__(256) void k_knn(const float* __restrict__ x, float* __restrict__ A)
{
    int g  = blockIdx.x >> 3;
    int i0 = (blockIdx.x & 7) * 16;
    __shared__ float xg[NPG * FIN];
    __shared__ float sq[NPG];
    __shared__ float D[16][NPG];
    const float* xp = x + g * NPG * FIN;
    for (int t = threadIdx.x; t < NPG * FIN; t += 256) xg[t] = xp[t];
    __syncthreads();
    if (threadIdx.x < NPG) {
        float s = 0.f;
        #pragma unroll
        for (int c = 0; c < FIN; ++c) { float v = xg[threadIdx.x * FIN + c]; s = fmaf(v, v, s); }
        sq[threadIdx.x] = s;
    }
    __syncthreads();
    for (int e = threadIdx.x; e < 16 * NPG; e += 256) {
        int il = e >> 7, j = e & 127;
        int i = i0 + il;
        float d;
        if (j == i) d = BIG;
        else {
            float dot = 0.f;
            #pragma unroll
            for (int c = 0; c < FIN; ++c) dot = fmaf(xg[i * FIN + c], xg[j * FIN + c], dot);
            d = sq[i] + sq[j] - 2.f * dot;
        }
        D[il][j] = d;
    }
    __syncthreads();
    float* Ag = A + (size_t)g * NPG * NPG;
    for (int e = threadIdx.x; e < 16 * NPG; e += 256) {
        int il = e >> 7, j = e & 127;
        int i = i0 + il;
        float aval;
        if (i == j) aval = INV101;
        else {
            float dj = D[il][j];
            int cnt = 0;
            #pragma unroll 8
            for (int k = 0; k < NPG; ++k) {
                float dk = D[il][k];
                cnt += (dk < dj || (dk == dj && k < j)) ? 1 : 0;
            }
            aval = (cnt < KNN) ? INV101 : 0.f;
        }
        Ag[i * NPG + j] = aval;
    }
}

// ---------------- K2: A2 = A @ A  (per graph; 2 blocks/graph, 64 rows each) ----------------
__global__ __launch_bounds__(256) void k_sqA(const float* __restrict__ A, float* __restrict__ A2)
{
    int g = blockIdx.x >> 1;
    int i0 = (blockIdx.x & 1) * 64;
    __shared__ float As[64 * 129];
    __shared__ float Bs[NPG * 132];
    const float* Ag = A + (size_t)g * NPG * NPG;
    for (int t = threadIdx.x; t < NPG * NPG; t += 256) {
        int r = t >> 7, c = t & 127;
        Bs[r * 132 + c] = Ag[t];
    }
    for (int t = threadIdx.x; t < 64 * NPG; t += 256) {
        int r = t >> 7, c = t & 127;
        As[r * 129 + c] = Ag[(i0 + r) * NPG + c];
    }
    __syncthreads();
    int ty = threadIdx.x >> 4, tx = threadIdx.x & 15;
    int lr = ty * 4, cj = tx * 8;
    float acc[4][8] = {};
    for (int k = 0; k < NPG; ++k) {
        float a[4], bb[8];
        #pragma unroll
        for (int r = 0; r < 4; ++r) a[r] = As[(lr + r) * 129 + k];
        float4 b0 = *(const float4*)&Bs[k * 132 + cj];
        float4 b1 = *(const float4*)&Bs[k * 132 + cj + 4];
        bb[0]=b0.x; bb[1]=b0.y; bb[2]=b0.z; bb[3]=b0.w;
        bb[4]=b1.x; bb[5]=b1.y; bb[6]=b1.z; bb[7]=b1.w;
        #pragma unroll
        for (int r = 0; r < 4; ++r)
            #pragma unroll
            for (int c = 0; c < 8; ++c)
                acc[r][c] = fmaf(a[r], bb[c], acc[r][c]);
    }
    float* A2g = A2 + (size_t)g * NPG * NPG;
    #pragma unroll
    for (int r = 0; r < 4; ++r) {
        float4 v0 = {acc[r][0], acc[r][1], acc[r][2], acc[r][3]};
        float4 v1 = {acc[r][4], acc[r][5], acc[r][6], acc[r][7]};
        *(float4*)&A2g[(i0 + lr + r) * NPG + cj]     = v0;
        *(float4*)&A2g[(i0 + lr + r) * NPG + cj + 4] = v1;
    }
}

// ---------------- K3: conv1 = leaky(A2 @ x @ W1 + b1) -> H ----------------
__global__ __launch_bounds__(256) void k_conv1(const float* __restrict__ x, const float* __restrict__ A2,
                                               const float* __restrict__ W1, const float* __restrict__ b1,
                                               float* __restrict__ H)
{
    int g = blockIdx.x;
    __shared__ float xg[NPG * FIN];
    __shared__ float p2[NPG * FIN];
    const float* xp = x + g * NPG * FIN;
    for (int t = threadIdx.x; t < NPG * FIN; t += 256) xg[t] = xp[t];
    __syncthreads();
    const float* A2g = A2 + (size_t)g * NPG * NPG;
    for (int e = threadIdx.x; e < NPG * FIN; e += 256) {
        int i = e / FIN, d = e - i * FIN;
        float s = 0.f;
        for (int k = 0; k < NPG; ++k) s = fmaf(A2g[i * NPG + k], xg[k * FIN + d], s);
        p2[e] = s;
    }
    __syncthreads();
    for (int e = threadIdx.x; e < NPG * WID; e += 256) {
        int i = e >> 7, o = e & 127;
        float s = b1[o];
        #pragma unroll
        for (int d = 0; d < FIN; ++d) s = fmaf(p2[i * FIN + d], W1[d * WID + o], s);
        H[(size_t)(g * NPG + i) * WID + o] = leaky(s);
    }
}

// ---------------- K4/K5: conv = leaky(A2 @ h @ W + b); pools PREVIOUS h at zoff ----------------
// grid 128 (2 blocks/graph, 64 output rows each), block 256
__global__ __launch_bounds__(256) void k_conv(const float* __restrict__ A2, const float* __restrict__ Hin,
                                              const float* __restrict__ W, const float* __restrict__ bias,
                                              float* __restrict__ Hout, float* __restrict__ Zp, int zoff)
{
    int g = blockIdx.x >> 1;
    int i0 = (blockIdx.x & 1) * 64;
    __shared__ float Ps[64 * 129];   // A2 half-rows, then P = A2 @ h
    __shared__ float hs[NPG * 132];  // full input h
    const float* A2g = A2 + (size_t)g * NPG * NPG + (size_t)i0 * NPG;
    const float* hg  = Hin + (size_t)g * NPG * WID;
    for (int t = threadIdx.x; t < NPG * WID; t += 256) {
        int r = t >> 7, c = t & 127;
        hs[r * 132 + c] = hg[t];
    }
    for (int t = threadIdx.x; t < 64 * NPG; t += 256) {
        int r = t >> 7, c = t & 127;
        Ps[r * 129 + c] = A2g[t];
    }
    __syncthreads();
    // fused pool of the INPUT h (previous layer's output); one block per graph does it
    if (i0 == 0 && threadIdx.x < WID) {
        int o = threadIdx.x;
        float sm = 0.f, mx = -BIG;
        for (int i = 0; i < NPG; ++i) { float v = hs[i * 132 + o]; sm += v; mx = fmaxf(mx, v); }
        Zp[g * D2 + zoff + o]       = sm * (1.f / NPG);
        Zp[g * D2 + zoff + WID + o] = mx;
    }
    int ty = threadIdx.x >> 4, tx = threadIdx.x & 15;
    int lr = ty * 4, cj = tx * 8;
    {   // P = A2 @ h  (64x128)
        float acc[4][8] = {};
        for (int k = 0; k < NPG; ++k) {
            float a[4], bb[8];
            #pragma unroll
            for (int r = 0; r < 4; ++r) a[r] = Ps[(lr + r) * 129 + k];
            float4 b0 = *(const float4*)&hs[k * 132 + cj];
            float4 b1 = *(const float4*)&hs[k * 132 + cj + 4];
            bb[0]=b0.x; bb[1]=b0.y; bb[2]=b0.z; bb[3]=b0.w;
            bb[4]=b1.x; bb[5]=b1.y; bb[6]=b1.z; bb[7]=b1.w;
            #pragma unroll
            for (int r = 0; r < 4; ++r)
                #pragma unroll
                for (int c = 0; c < 8; ++c)
                    acc[r][c] = fmaf(a[r], bb[c], acc[r][c]);
        }
        __syncthreads();
        #pragma unroll
        for (int r = 0; r < 4; ++r)
            #pragma unroll
            for (int c = 0; c < 8; ++c)
                Ps[(lr + r) * 129 + cj + c] = acc[r][c];
        __syncthreads();
    }
    {   // h' = leaky(P @ W + b) -> Hout
        float acc[4][8] = {};
        for (int d = 0; d < NPG; ++d) {
            float a[4], bb[8];
            #pragma unroll
            for (int r = 0; r < 4; ++r) a[r] = Ps[(lr + r) * 129 + d];
            float4 w0 = *(const float4*)&W[d * WID + cj];
            float4 w1 = *(const float4*)&W[d * WID + cj + 4];
            bb[0]=w0.x; bb[1]=w0.y; bb[2]=w0.z; bb[3]=w0.w;
            bb[4]=w1.x; bb[5]=w1.y; bb[6]=w1.z; bb[7]=w1.w;
            #pragma unroll
            for (int r = 0; r < 4; ++r)
                #pragma unroll
                for (int c = 0; c < 8; ++c)
                    acc[r][c] = fmaf(a[r], bb[c], acc[r][c]);
        }
        #pragma unroll
        for (int r = 0; r < 4; ++r) {
            float4 v0, v1;
            v0.x = leaky(acc[r][0] + bias[cj + 0]);
            v0.y = leaky(acc[r][1] + bias[cj + 1]);
            v0.z = leaky(acc[r][2] + bias[cj + 2]);
            v0.w = leaky(acc[r][3] + bias[cj + 3]);
            v1.x = leaky(acc[r][4] + bias[cj + 4]);
            v1.y = leaky(acc[r][5] + bias[cj + 5]);
            v1.z = leaky(acc[r][6] + bias[cj + 6]);
            v1.w = leaky(acc[r][7] + bias[cj + 7]);
            *(float4*)&Hout[(size_t)(g * NPG + i0 + lr + r) * WID + cj]     = v0;
            *(float4*)&Hout[(size_t)(g * NPG + i0 + lr + r) * WID + cj + 4] = v1;
        }
    }
}

// ---------------- K6: pool of final h -> Zp[:, zoff..zoff+256) ----------------
__global__ __launch_bounds__(128) void k_pool(const float* __restrict__ H, float* __restrict__ Zp, int zoff)
{
    int g = blockIdx.x, o = threadIdx.x;
    float sm = 0.f, mx = -BIG;
    for (int i = 0; i < NPG; ++i) {
        float v = H[((size_t)g * NPG + i) * WID + o];
        sm += v; mx = fmaxf(mx, v);
    }
    Zp[g * D2 + zoff + o]       = sm * (1.f / NPG);
    Zp[g * D2 + zoff + WID + o] = mx;
}

// ---------------- K7: BatchNorm (batch stats) + transpose to ZT[768][64] ----------------
// grid 6 x 128
__global__ __launch_bounds__(128) void k_bn(const float* __restrict__ Zp, const float* __restrict__ gam,
                                            const float* __restrict__ bet, float* __restrict__ ZT)
{
    int c = blockIdx.x * 128 + threadIdx.x;
    float s = 0.f, s2 = 0.f;
    for (int r = 0; r < NG; ++r) { float v = Zp[r * D2 + c]; s += v; s2 = fmaf(v, v, s2); }
    float m   = s * (1.f / NG);
    float var = s2 * (1.f / NG) - m * m;
    float sc  = rsqrtf(var + BNEPS) * gam[c];
    float bt  = bet[c];
    for (int r = 0; r < NG; ++r) {
        float v = Zp[r * D2 + c];
        ZT[c * NG + r] = (v - m) * sc + bt;
    }
}

// ---------------- K8a: MLP layer partial GEMM (split-K) ----------------
// grid (48, 8): x = 16-col slab, y = k-slice of 96. block 256.
// Lanes 0-15 read one full 64B W line per k (exactly-once W read).
__global__ __launch_bounds__(256) void k_linA(const float* __restrict__ ZTin, const float* __restrict__ W,
                                              float* __restrict__ P)
{
    const int c  = blockIdx.x * 16 + (threadIdx.x & 15);
    const int r0 = (threadIdx.x >> 4) * 4;
    const int k0 = blockIdx.y * 96;
    const float* wp = W + (size_t)k0 * D2 + c;
    const float* zp = ZTin + k0 * NG + r0;
    float4 acc = {0.f, 0.f, 0.f, 0.f};
    for (int kk = 0; kk < 96; kk += 16) {
        float  wv[16];
        float4 zv[16];
        #pragma unroll
        for (int u = 0; u < 16; ++u) {
            wv[u] = wp[(kk + u) * D2];
            zv[u] = *(const float4*)&zp[(kk + u) * NG];
        }
        #pragma unroll
        for (int u = 0; u < 16; ++u) {
            acc.x = fmaf(zv[u].x, wv[u], acc.x);
            acc.y = fmaf(zv[u].y, wv[u], acc.y);
            acc.z = fmaf(zv[u].z, wv[u], acc.z);
            acc.w = fmaf(zv[u].w, wv[u], acc.w);
        }
    }
    *(float4*)&P[((size_t)blockIdx.y * D2 + c) * NG + r0] = acc;
}

// ---------------- K8b: reduce 8 partial planes + bias + leaky ----------------
// grid 48 x 256; thread handles 4 consecutive elements (same output column)
__global__ __launch_bounds__(256) void k_linB(const float* __restrict__ P, const float* __restrict__ bias,
                                              float* __restrict__ ZTout)
{
    int e = (blockIdx.x * 256 + threadIdx.x) * 4;
    float4 s = *(const float4*)&P[e];
    #pragma unroll
    for (int q = 1; q < 8; ++q) {
        float4 p = *(const float4*)&P[(size_t)q * (D2 * NG) + e];
        s.x += p.x; s.y += p.y; s.z += p.z; s.w += p.w;
    }
    float bv = bias[e >> 6];
    s.x = leaky(s.x + bv); s.y = leaky(s.y + bv);
    s.z = leaky(s.z + bv); s.w = leaky(s.w + bv);
    *(float4*)&ZTout[e] = s;
}

// ---------------- K9: output head (split-K across 4 waves) ----------------
__global__ __launch_bounds__(256) void k_out(const float* __restrict__ ZTin, const float* __restrict__ W,
                                             const float* __restrict__ bias, float* __restrict__ out)
{
    __shared__ float red[4][64];
    int r = threadIdx.x & 63, q = threadIdx.x >> 6;
    float s = 0.f;
    #pragma unroll 8
    for (int k = q * 192; k < q * 192 + 192; ++k)
        s = fmaf(ZTin[k * NG + r], W[k], s);
    red[q][r] = s;
    __syncthreads();
    if (threadIdx.x < 64)
        out[r] = red[0][r] + red[1][r] + red[2][r] + red[3][r] + bias[0];
}

extern "C" void kernel_launch(void* const* d_in, const int* in_sizes, int n_in,
                              void* d_out, int out_size, void* d_ws, size_t ws_size,
                              hipStream_t stream)
{
    (void)in_sizes; (void)n_in; (void)out_size; (void)ws_size;
    const float* x       = (const float*)d_in[0];
    // d_in[1] = batch: structure is fixed (i / 128), unused
    const float* conv1_W = (const float*)d_in[2];
    const float* conv1_b = (const float*)d_in[3];
    const float* convs_W = (const float*)d_in[4];
    const float* convs_b = (const float*)d_in[5];
    const float* bn_g    = (const float*)d_in[6];
    const float* bn_b    = (const float*)d_in[7];
    const float* lin_W   = (const float*)d_in[8];
    const float* lin_b   = (const float*)d_in[9];
    const float* out_W   = (const float*)d_in[10];
    const float* out_b   = (const float*)d_in[11];

    // workspace (floats): A_raw (1M; later H_b, later P), A2 (1M), H_a (1M), Zp, ZT0, ZT1
    float* A_raw = (float*)d_ws;
    float* A2    = A_raw + (1 << 20);
    float* H_a   = A2 + (1 << 20);
    float* H_b   = A_raw;            // A_raw dead after k_sqA
    float* P     = A_raw;            // H_b dead after second k_conv
    float* Zp    = H_a + (1 << 20);
    float* ZT0   = Zp + NG * D2;
    float* ZT1   = ZT0 + NG * D2;

    k_knn  <<<dim3(512), dim3(256), 0, stream>>>(x, A_raw);
    k_sqA  <<<dim3(128), dim3(256), 0, stream>>>(A_raw, A2);
    k_conv1<<<dim3(NG),  dim3(256), 0, stream>>>(x, A2, conv1_W, conv1_b, H_a);
    k_conv <<<dim3(128), dim3(256), 0, stream>>>(A2, H_a, convs_W,             convs_b,       H_b, Zp, 0);
    k_conv <<<dim3(128), dim3(256), 0, stream>>>(A2, H_b, convs_W + WID * WID, convs_b + WID, H_a, Zp, 256);
    k_pool <<<dim3(NG),  dim3(128), 0, stream>>>(H_a, Zp, 512);
    k_bn   <<<dim3(6),   dim3(128), 0, stream>>>(Zp, bn_g, bn_b, ZT0);

    const float* zin = ZT0; float* zout = ZT1;
    for (int l = 0; l < 5; ++l) {
        k_linA<<<dim3(48, 8), dim3(256), 0, stream>>>(zin, lin_W + (size_t)l * D2 * D2, P);
        k_linB<<<dim3(48),    dim3(256), 0, stream>>>(P, lin_b + l * D2, zout);
        float* t = zout; zout = (float*)zin; zin = t;
    }
    k_out<<<dim3(1), dim3(256), 0, stream>>>(zin, out_W, out_b, (float*)d_out);
}

// Round 4
// 172.218 us; speedup vs baseline: 3.2793x; 1.1107x over previous
//
#include <hip/hip_runtime.h>

#define NN    8192
#define NG    64
#define NPG   128
#define KNN   100
#define FIN   6
#define WID   128
#define D2    768
#define NEG   0.01f
#define INV101 (1.0f/101.0f)
#define BNEPS 1e-5f
#define BIG   1e30f

__device__ __forceinline__ float leaky(float v) { return v > 0.f ? v : NEG * v; }

// ---------------- K1: kNN (rank-select) + normalized adjacency A = (I+M)/101 ----------------
// grid 512 (8 blocks/graph, 16 rows each), block 256
__global__ __launch_bounds__(256) void k_knn(const float* __restrict__ x, float* __restrict__ A)
{
    int g  = blockIdx.x >> 3;
    int i0 = (blockIdx.x & 7) * 16;
    __shared__ float xg[NPG * FIN];
    __shared__ float sq[NPG];
    __shared__ float D[16][NPG];
    const float* xp = x + g * NPG * FIN;
    for (int t = threadIdx.x; t < NPG * FIN; t += 256) xg[t] = xp[t];
    __syncthreads();
    if (threadIdx.x < NPG) {
        float s = 0.f;
        #pragma unroll
        for (int c = 0; c < FIN; ++c) { float v = xg[threadIdx.x * FIN + c]; s = fmaf(v, v, s); }
        sq[threadIdx.x] = s;
    }
    __syncthreads();
    for (int e = threadIdx.x; e < 16 * NPG; e += 256) {
        int il = e >> 7, j = e & 127;
        int i = i0 + il;
        float d;
        if (j == i) d = BIG;
        else {
            float dot = 0.f;
            #pragma unroll
            for (int c = 0; c < FIN; ++c) dot = fmaf(xg[i * FIN + c], xg[j * FIN + c], dot);
            d = sq[i] + sq[j] - 2.f * dot;
        }
        D[il][j] = d;
    }
    __syncthreads();
    float* Ag = A + (size_t)g * NPG * NPG;
    for (int e = threadIdx.x; e < 16 * NPG; e += 256) {
        int il = e >> 7, j = e & 127;
        int i = i0 + il;
        float aval;
        if (i == j) aval = INV101;
        else {
            float dj = D[il][j];
            int cnt = 0;
            #pragma unroll 8
            for (int k = 0; k < NPG; ++k) {
                float dk = D[il][k];
                cnt += (dk < dj || (dk == dj && k < j)) ? 1 : 0;
            }
            aval = (cnt < KNN) ? INV101 : 0.f;
        }
        Ag[i * NPG + j] = aval;
    }
}

// ---------------- K2: fused A2 = A@A slab  +  conv1 h1 = leaky(A2 @ x @ W1 + b1) ----------------
// grid 256 (4 blocks/graph, 32-row slab), block 256. Writes A2 (for convs) and H (h1).
__global__ __launch_bounds__(256) void k_sqA_c1(const float* __restrict__ A, const float* __restrict__ x,
                                                const float* __restrict__ W1, const float* __restrict__ b1,
                                                float* __restrict__ A2, float* __restrict__ H)
{
    int g  = blockIdx.x >> 2;
    int i0 = (blockIdx.x & 2) << 4;  // (blockIdx&3)*32
    i0 = (blockIdx.x & 3) * 32;
    __shared__ float As[32 * 132];   // A slab rows, then A2 slab (pad 132: 16B-aligned rows)
    __shared__ float Bs[NPG * NPG];  // full A (row-contiguous reads -> no pad needed)
    __shared__ float xg[NPG * FIN];
    __shared__ float p2[32 * FIN];
    __shared__ float W1s[FIN * WID];
    __shared__ float b1s[WID];
    const float* Ag = A + (size_t)g * NPG * NPG;
    const float* xp = x + g * NPG * FIN;
    for (int t4 = threadIdx.x; t4 < NPG * NPG / 4; t4 += 256)
        *(float4*)&Bs[t4 * 4] = *(const float4*)&Ag[t4 * 4];
    for (int t4 = threadIdx.x; t4 < 32 * 32; t4 += 256) {
        int r = t4 >> 5, c4 = (t4 & 31) * 4;
        *(float4*)&As[r * 132 + c4] = *(const float4*)&Ag[(i0 + r) * NPG + c4];
    }
    for (int t = threadIdx.x; t < NPG * FIN; t += 256) xg[t] = xp[t];
    for (int t = threadIdx.x; t < FIN * WID; t += 256) W1s[t] = W1[t];
    if (threadIdx.x < WID) b1s[threadIdx.x] = b1[threadIdx.x];
    __syncthreads();

    int ty = threadIdx.x >> 4, tx = threadIdx.x & 15;
    int r0 = ty * 2, cj = tx * 8;
    float acc[2][8] = {};
    for (int k = 0; k < NPG; ++k) {
        float a0 = As[r0 * 132 + k];
        float a1 = As[(r0 + 1) * 132 + k];
        float4 q0 = *(const float4*)&Bs[k * NPG + cj];
        float4 q1 = *(const float4*)&Bs[k * NPG + cj + 4];
        float bb[8] = {q0.x, q0.y, q0.z, q0.w, q1.x, q1.y, q1.z, q1.w};
        #pragma unroll
        for (int c = 0; c < 8; ++c) {
            acc[0][c] = fmaf(a0, bb[c], acc[0][c]);
            acc[1][c] = fmaf(a1, bb[c], acc[1][c]);
        }
    }
    // write A2 slab to global (needed by k_conv)
    float* A2g = A2 + (size_t)g * NPG * NPG;
    #pragma unroll
    for (int r = 0; r < 2; ++r) {
        float4 v0 = {acc[r][0], acc[r][1], acc[r][2], acc[r][3]};
        float4 v1 = {acc[r][4], acc[r][5], acc[r][6], acc[r][7]};
        *(float4*)&A2g[(i0 + r0 + r) * NPG + cj]     = v0;
        *(float4*)&A2g[(i0 + r0 + r) * NPG + cj + 4] = v1;
    }
    __syncthreads();   // all reads of As (A slab) done
    #pragma unroll
    for (int r = 0; r < 2; ++r) {
        *(float4*)&As[(r0 + r) * 132 + cj]     = make_float4(acc[r][0], acc[r][1], acc[r][2], acc[r][3]);
        *(float4*)&As[(r0 + r) * 132 + cj + 4] = make_float4(acc[r][4], acc[r][5], acc[r][6], acc[r][7]);
    }
    __syncthreads();   // As now holds A2 slab
    // p2 = A2_slab @ x   (32 x 6)
    if (threadIdx.x < 32 * FIN) {
        int i = threadIdx.x / FIN, d = threadIdx.x - i * FIN;
        float s = 0.f;
        for (int k = 0; k < NPG; ++k) s = fmaf(As[i * 132 + k], xg[k * FIN + d], s);
        p2[threadIdx.x] = s;
    }
    __syncthreads();
    // h1 = leaky(p2 @ W1 + b1) -> H
    for (int e = threadIdx.x; e < 32 * WID; e += 256) {
        int i = e >> 7, o = e & 127;
        float s = b1s[o];
        #pragma unroll
        for (int d = 0; d < FIN; ++d) s = fmaf(p2[i * FIN + d], W1s[d * WID + o], s);
        H[(size_t)(g * NPG + i0 + i) * WID + o] = leaky(s);
    }
}

// ---------------- K3/K4: conv = leaky(A2 @ h @ W + b); pools INPUT h at zoff ----------------
// grid 256 (4 blocks/graph, 32-row slab), block 256
__global__ __launch_bounds__(256) void k_conv(const float* __restrict__ A2, const float* __restrict__ Hin,
                                              const float* __restrict__ W, const float* __restrict__ bias,
                                              float* __restrict__ Hout, float* __restrict__ Zp, int zoff)
{
    int g  = blockIdx.x >> 2;
    int i0 = (blockIdx.x & 3) * 32;
    __shared__ float Ps[32 * 132];   // A2 slab, then P = A2 @ h slab
    __shared__ float hs[NPG * WID];  // full input h (row-contiguous reads)
    const float* A2g = A2 + (size_t)g * NPG * NPG;
    const float* hg  = Hin + (size_t)g * NPG * WID;
    for (int t4 = threadIdx.x; t4 < NPG * WID / 4; t4 += 256)
        *(float4*)&hs[t4 * 4] = *(const float4*)&hg[t4 * 4];
    for (int t4 = threadIdx.x; t4 < 32 * 32; t4 += 256) {
        int r = t4 >> 5, c4 = (t4 & 31) * 4;
        *(float4*)&Ps[r * 132 + c4] = *(const float4*)&A2g[(i0 + r) * NPG + c4];
    }
    __syncthreads();
    // fused pool of the INPUT h; first block of each graph
    if ((blockIdx.x & 3) == 0 && threadIdx.x < WID) {
        int o = threadIdx.x;
        float sm = 0.f, mx = -BIG;
        for (int i = 0; i < NPG; ++i) { float v = hs[i * WID + o]; sm += v; mx = fmaxf(mx, v); }
        Zp[g * D2 + zoff + o]       = sm * (1.f / NPG);
        Zp[g * D2 + zoff + WID + o] = mx;
    }
    int ty = threadIdx.x >> 4, tx = threadIdx.x & 15;
    int r0 = ty * 2, cj = tx * 8;
    float acc[2][8];
    {   // P = A2_slab @ h
        #pragma unroll
        for (int r = 0; r < 2; ++r)
            #pragma unroll
            for (int c = 0; c < 8; ++c) acc[r][c] = 0.f;
        for (int k = 0; k < NPG; ++k) {
            float a0 = Ps[r0 * 132 + k];
            float a1 = Ps[(r0 + 1) * 132 + k];
            float4 q0 = *(const float4*)&hs[k * WID + cj];
            float4 q1 = *(const float4*)&hs[k * WID + cj + 4];
            float bb[8] = {q0.x, q0.y, q0.z, q0.w, q1.x, q1.y, q1.z, q1.w};
            #pragma unroll
            for (int c = 0; c < 8; ++c) {
                acc[0][c] = fmaf(a0, bb[c], acc[0][c]);
                acc[1][c] = fmaf(a1, bb[c], acc[1][c]);
            }
        }
        __syncthreads();   // all reads of Ps (A2) done
        #pragma unroll
        for (int r = 0; r < 2; ++r) {
            *(float4*)&Ps[(r0 + r) * 132 + cj]     = make_float4(acc[r][0], acc[r][1], acc[r][2], acc[r][3]);
            *(float4*)&Ps[(r0 + r) * 132 + cj + 4] = make_float4(acc[r][4], acc[r][5], acc[r][6], acc[r][7]);
        }
        __syncthreads();
    }
    {   // h' = leaky(P @ W + b) -> Hout
        float o2[2][8];
        #pragma unroll
        for (int r = 0; r < 2; ++r)
            #pragma unroll
            for (int c = 0; c < 8; ++c) o2[r][c] = 0.f;
        for (int d = 0; d < NPG; ++d) {
            float a0 = Ps[r0 * 132 + d];
            float a1 = Ps[(r0 + 1) * 132 + d];
            float4 w0 = *(const float4*)&W[d * WID + cj];
            float4 w1 = *(const float4*)&W[d * WID + cj + 4];
            float bb[8] = {w0.x, w0.y, w0.z, w0.w, w1.x, w1.y, w1.z, w1.w};
            #pragma unroll
            for (int c = 0; c < 8; ++c) {
                o2[0][c] = fmaf(a0, bb[c], o2[0][c]);
                o2[1][c] = fmaf(a1, bb[c], o2[1][c]);
            }
        }
        #pragma unroll
        for (int r = 0; r < 2; ++r) {
            float4 v0, v1;
            v0.x = leaky(o2[r][0] + bias[cj + 0]);
            v0.y = leaky(o2[r][1] + bias[cj + 1]);
            v0.z = leaky(o2[r][2] + bias[cj + 2]);
            v0.w = leaky(o2[r][3] + bias[cj + 3]);
            v1.x = leaky(o2[r][4] + bias[cj + 4]);
            v1.y = leaky(o2[r][5] + bias[cj + 5]);
            v1.z = leaky(o2[r][6] + bias[cj + 6]);
            v1.w = leaky(o2[r][7] + bias[cj + 7]);
            *(float4*)&Hout[(size_t)(g * NPG + i0 + r0 + r) * WID + cj]     = v0;
            *(float4*)&Hout[(size_t)(g * NPG + i0 + r0 + r) * WID + cj + 4] = v1;
        }
    }
}

// ---------------- K5: pool of final h -> Zp[:, zoff..zoff+256) ----------------
__global__ __launch_bounds__(128) void k_pool(const float* __restrict__ H, float* __restrict__ Zp, int zoff)
{
    int g = blockIdx.x, o = threadIdx.x;
    float sm = 0.f, mx = -BIG;
    for (int i = 0; i < NPG; ++i) {
        float v = H[((size_t)g * NPG + i) * WID + o];
        sm += v; mx = fmaxf(mx, v);
    }
    Zp[g * D2 + zoff + o]       = sm * (1.f / NPG);
    Zp[g * D2 + zoff + WID + o] = mx;
}

// ---------------- K6: BatchNorm (batch stats) + transpose to ZT[768][64] ----------------
__global__ __launch_bounds__(128) void k_bn(const float* __restrict__ Zp, const float* __restrict__ gam,
                                            const float* __restrict__ bet, float* __restrict__ ZT)
{
    int c = blockIdx.x * 128 + threadIdx.x;
    float s = 0.f, s2 = 0.f;
    for (int r = 0; r < NG; ++r) { float v = Zp[r * D2 + c]; s += v; s2 = fmaf(v, v, s2); }
    float m   = s * (1.f / NG);
    float var = s2 * (1.f / NG) - m * m;
    float sc  = rsqrtf(var + BNEPS) * gam[c];
    float bt  = bet[c];
    for (int r = 0; r < NG; ++r) {
        float v = Zp[r * D2 + c];
        ZT[c * NG + r] = (v - m) * sc + bt;
    }
}

// ---------------- K7a: MLP layer partial GEMM (split-K x16) ----------------
// grid (48, 16): x = 16-col slab, y = 48-k slice. block 256.
// Lanes 0-15 cover one 64B W line per k; 3 chunks of 32 in-flight loads.
__global__ __launch_bounds__(256) void k_linA(const float* __restrict__ ZTin, const float* __restrict__ W,
                                              float* __restrict__ P)
{
    const int c  = blockIdx.x * 16 + (threadIdx.x & 15);
    const int r0 = (threadIdx.x >> 4) * 4;
    const int k0 = blockIdx.y * 48;
    const float* wp = W + (size_t)k0 * D2 + c;
    const float* zp = ZTin + k0 * NG + r0;
    float4 acc = {0.f, 0.f, 0.f, 0.f};
    #pragma unroll
    for (int kk = 0; kk < 48; kk += 16) {
        float  wv[16];
        float4 zv[16];
        #pragma unroll
        for (int u = 0; u < 16; ++u) {
            wv[u] = wp[(kk + u) * D2];
            zv[u] = *(const float4*)&zp[(kk + u) * NG];
        }
        #pragma unroll
        for (int u = 0; u < 16; ++u) {
            acc.x = fmaf(zv[u].x, wv[u], acc.x);
            acc.y = fmaf(zv[u].y, wv[u], acc.y);
            acc.z = fmaf(zv[u].z, wv[u], acc.z);
            acc.w = fmaf(zv[u].w, wv[u], acc.w);
        }
    }
    *(float4*)&P[((size_t)blockIdx.y * D2 + c) * NG + r0] = acc;
}

// ---------------- K7b: reduce 16 partial planes + bias + leaky ----------------
__global__ __launch_bounds__(256) void k_linB(const float* __restrict__ P, const float* __restrict__ bias,
                                              float* __restrict__ ZTout)
{
    int e = (blockIdx.x * 256 + threadIdx.x) * 4;
    float4 s = *(const float4*)&P[e];
    #pragma unroll
    for (int q = 1; q < 16; ++q) {
        float4 p = *(const float4*)&P[(size_t)q * (D2 * NG) + e];
        s.x += p.x; s.y += p.y; s.z += p.z; s.w += p.w;
    }
    float bv = bias[e >> 6];
    s.x = leaky(s.x + bv); s.y = leaky(s.y + bv);
    s.z = leaky(s.z + bv); s.w = leaky(s.w + bv);
    *(float4*)&ZTout[e] = s;
}

// ---------------- K8: output head (split-K across 4 waves) ----------------
__global__ __launch_bounds__(256) void k_out(const float* __restrict__ ZTin, const float* __restrict__ W,
                                             const float* __restrict__ bias, float* __restrict__ out)
{
    __shared__ float red[4][64];
    int r = threadIdx.x & 63, q = threadIdx.x >> 6;
    float s = 0.f;
    #pragma unroll 8
    for (int k = q * 192; k < q * 192 + 192; ++k)
        s = fmaf(ZTin[k * NG + r], W[k], s);
    red[q][r] = s;
    __syncthreads();
    if (threadIdx.x < 64)
        out[r] = red[0][r] + red[1][r] + red[2][r] + red[3][r] + bias[0];
}

extern "C" void kernel_launch(void* const* d_in, const int* in_sizes, int n_in,
                              void* d_out, int out_size, void* d_ws, size_t ws_size,
                              hipStream_t stream)
{
    (void)in_sizes; (void)n_in; (void)out_size; (void)ws_size;
    const float* x       = (const float*)d_in[0];
    // d_in[1] = batch: structure is fixed (i / 128), unused
    const float* conv1_W = (const float*)d_in[2];
    const float* conv1_b = (const float*)d_in[3];
    const float* convs_W = (const float*)d_in[4];
    const float* convs_b = (const float*)d_in[5];
    const float* bn_g    = (const float*)d_in[6];
    const float* bn_b    = (const float*)d_in[7];
    const float* lin_W   = (const float*)d_in[8];
    const float* lin_b   = (const float*)d_in[9];
    const float* out_W   = (const float*)d_in[10];
    const float* out_b   = (const float*)d_in[11];

    // workspace (floats): A_raw (1M; later H_b, later P 3M->use 1M? P=16 planes*48K=768K ok),
    // A2 (1M), H_a (1M), Zp, ZT0, ZT1
    float* A_raw = (float*)d_ws;
    float* A2    = A_raw + (1 << 20);
    float* H_a   = A2 + (1 << 20);
    float* H_b   = A_raw;            // A_raw dead after k_sqA_c1
    float* P     = A_raw;            // H_b dead after second k_conv (16*768*64 = 768K floats < 1M)
    float* Zp    = H_a + (1 << 20);
    float* ZT0   = Zp + NG * D2;
    float* ZT1   = ZT0 + NG * D2;

    k_knn   <<<dim3(512), dim3(256), 0, stream>>>(x, A_raw);
    k_sqA_c1<<<dim3(256), dim3(256), 0, stream>>>(A_raw, x, conv1_W, conv1_b, A2, H_a);
    k_conv  <<<dim3(256), dim3(256), 0, stream>>>(A2, H_a, convs_W,             convs_b,       H_b, Zp, 0);
    k_conv  <<<dim3(256), dim3(256), 0, stream>>>(A2, H_b, convs_W + WID * WID, convs_b + WID, H_a, Zp, 256);
    k_pool  <<<dim3(NG),  dim3(128), 0, stream>>>(H_a, Zp, 512);
    k_bn    <<<dim3(6),   dim3(128), 0, stream>>>(Zp, bn_g, bn_b, ZT0);

    const float* zin = ZT0; float* zout = ZT1;
    for (int l = 0; l < 5; ++l) {
        k_linA<<<dim3(48, 16), dim3(256), 0, stream>>>(zin, lin_W + (size_t)l * D2 * D2, P);
        k_linB<<<dim3(48),     dim3(256), 0, stream>>>(P, lin_b + l * D2, zout);
        float* t = zout; zout = (float*)zin; zin = t;
    }
    k_out<<<dim3(1), dim3(256), 0, stream>>>(zin, out_W, out_b, (float*)d_out);
}